// Round 6
// baseline (1991.910 us; speedup 1.0000x reference)
//
#include <hip/hip_runtime.h>
#include <math.h>

#define NN 16384
#define EE 262144
#define HH 256

#define INV_SQRT_3f 0.57735026918962576f
#define INV_SQRT_Hf 0.0625f
#define INV_SQRT_2f 0.70710678118654752f
#define SSILU_SCALE 1.6666666666666667f

typedef __attribute__((ext_vector_type(8))) short bf16x8;
typedef __attribute__((ext_vector_type(4))) float f32x4;

__device__ __forceinline__ float ssilu_f(float v) {
    return v * (1.0f / (1.0f + __expf(-v))) * SSILU_SCALE;
}
__device__ __forceinline__ float b2f(short s) {
    unsigned int u = ((unsigned int)(unsigned short)s) << 16;
    return __uint_as_float(u);
}
__device__ __forceinline__ short f2b(float f) {
    unsigned int u = __float_as_uint(f);
    unsigned int r = (u + 0x7fff + ((u >> 16) & 1)) >> 16;
    return (short)r;
}

// ---------------- LayerNorm: one block per row, split-bf16 out ----------------
__global__ void __launch_bounds__(256) ln_kernel(const float* __restrict__ x,
                                                 const float* __restrict__ g,
                                                 const float* __restrict__ b,
                                                 short* __restrict__ oh,
                                                 short* __restrict__ ol) {
    int n = blockIdx.x;
    int t = threadIdx.x;
    float v = x[(long)n * HH + t];
    float s = v, s2 = v * v;
    #pragma unroll
    for (int off = 32; off > 0; off >>= 1) {
        s  += __shfl_down(s, off);
        s2 += __shfl_down(s2, off);
    }
    __shared__ float red[8];
    int wave = t >> 6, lane = t & 63;
    if (lane == 0) { red[wave] = s; red[4 + wave] = s2; }
    __syncthreads();
    __shared__ float mr[2];
    if (t == 0) {
        float ts = red[0] + red[1] + red[2] + red[3];
        float ts2 = red[4] + red[5] + red[6] + red[7];
        float mean = ts * (1.0f / HH);
        float var = ts2 * (1.0f / HH) - mean * mean;
        mr[0] = mean;
        mr[1] = rsqrtf(var + 1e-5f);
    }
    __syncthreads();
    float o = (v - mr[0]) * mr[1] * g[t] + b[t];
    short hh = f2b(o);
    oh[(long)n * HH + t] = hh;
    ol[(long)n * HH + t] = f2b(o - b2f(hh));
}

// ---- weight transpose + hi/lo split: WTh/WTl[n*K+k] from W[k*N+n] ----
__global__ void __launch_bounds__(256) wt_split_kernel(const float* __restrict__ W,
                                                       short* __restrict__ WTh,
                                                       short* __restrict__ WTl,
                                                       int K, int N) {
    int idx = blockIdx.x * 256 + threadIdx.x;
    int k = idx / N, n = idx % N;
    float w = W[idx];
    short hh = f2b(w);
    WTh[(long)n * K + k] = hh;
    WTl[(long)n * K + k] = f2b(w - b2f(hh));
}

// ---- fp32 -> hi/lo split (count % 1024 == 0) ----
__global__ void __launch_bounds__(256) split4_kernel(const float* __restrict__ in,
                                                     short* __restrict__ h,
                                                     short* __restrict__ l) {
    long i = ((long)blockIdx.x * 256 + threadIdx.x) * 4;
    float4 v = *(const float4*)(in + i);
    short4 oh, ol;
    oh.x = f2b(v.x); ol.x = f2b(v.x - b2f(oh.x));
    oh.y = f2b(v.y); ol.y = f2b(v.y - b2f(oh.y));
    oh.z = f2b(v.z); ol.z = f2b(v.z - b2f(oh.z));
    oh.w = f2b(v.w); ol.w = f2b(v.w - b2f(oh.w));
    *(short4*)(h + i) = oh;
    *(short4*)(l + i) = ol;
}

// ---- split-bf16 MFMA GEMM: C = (Ah+Al)(M,K) @ (Wh+Wl)^T(N,K) [+bias][ssilu]
// C ~= Ah@Wh + Al@Wh + Ah@Wl  (fp32-class precision)
// block 256 = 4 waves; 64x64 tile. M%64==0, N%64==0, K%32==0.
// out: Cl!=null -> split hi/lo; else act&2 -> bf16 single; else fp32.
__global__ void __launch_bounds__(256) mfma_gemm(const short* __restrict__ Ah,
                                                 const short* __restrict__ Al,
                                                 const short* __restrict__ Wh,
                                                 const short* __restrict__ Wl,
                                                 const float* __restrict__ bias,
                                                 void* __restrict__ Ch,
                                                 short* __restrict__ Cl,
                                                 int M, int K, int N, int act) {
    int tid = threadIdx.x;
    int wave = tid >> 6, lane = tid & 63;
    int quad = lane >> 4, l16 = lane & 15;
    long bm = (long)blockIdx.x * 64 + wave * 16;
    long bn = (long)blockIdx.y * 64;
    long aoff = (bm + l16) * K + quad * 8;
    long woff = (bn + l16) * K + quad * 8;

    f32x4 acc[4];
    #pragma unroll
    for (int t = 0; t < 4; t++) acc[t] = (f32x4){0.f, 0.f, 0.f, 0.f};

    for (int k0 = 0; k0 < K; k0 += 32) {
        bf16x8 ah = *(const bf16x8*)(Ah + aoff + k0);
        bf16x8 al = *(const bf16x8*)(Al + aoff + k0);
        #pragma unroll
        for (int t = 0; t < 4; t++) {
            long wo = woff + (long)t * 16 * K + k0;
            bf16x8 bh = *(const bf16x8*)(Wh + wo);
            bf16x8 bl = *(const bf16x8*)(Wl + wo);
            acc[t] = __builtin_amdgcn_mfma_f32_16x16x32_bf16(ah, bh, acc[t], 0, 0, 0);
            acc[t] = __builtin_amdgcn_mfma_f32_16x16x32_bf16(al, bh, acc[t], 0, 0, 0);
            acc[t] = __builtin_amdgcn_mfma_f32_16x16x32_bf16(ah, bl, acc[t], 0, 0, 0);
        }
    }

    long row0 = bm + quad * 4;
    #pragma unroll
    for (int t = 0; t < 4; t++) {
        long col = bn + t * 16 + l16;
        float bv = bias ? bias[col] : 0.f;
        #pragma unroll
        for (int r = 0; r < 4; r++) {
            float v = acc[t][r] + bv;
            if (act & 1) v = ssilu_f(v);
            long idx = (row0 + r) * N + col;
            if (Cl) {
                short hh = f2b(v);
                ((short*)Ch)[idx] = hh;
                Cl[idx] = f2b(v - b2f(hh));
            } else if (act & 2) {
                ((short*)Ch)[idx] = f2b(v);
            } else {
                ((float*)Ch)[idx] = v;
            }
        }
    }
}

// ---------------- edge sort (counting sort by dst) ----------------
__global__ void __launch_bounds__(256) zero_kernel(int* __restrict__ p, int n) {
    int i = blockIdx.x * 256 + threadIdx.x;
    if (i < n) p[i] = 0;
}

__global__ void __launch_bounds__(256) hist_kernel(const int* __restrict__ eidx,
                                                   int* __restrict__ cnt) {
    int e = blockIdx.x * 256 + threadIdx.x;
    atomicAdd(&cnt[eidx[EE + e]], 1);
}

__global__ void __launch_bounds__(256) scan_kernel(int* __restrict__ cursor,
                                                   int* __restrict__ rowptr) {
    int t = threadIdx.x;
    int base_i = t * 64;
    int tsum = 0;
    for (int i = 0; i < 64; i++) tsum += cursor[base_i + i];
    __shared__ int ls[256];
    ls[t] = tsum;
    __syncthreads();
    for (int off = 1; off < 256; off <<= 1) {
        int v = (t >= off) ? ls[t - off] : 0;
        __syncthreads();
        ls[t] += v;
        __syncthreads();
    }
    int running = ls[t] - tsum;
    for (int i = 0; i < 64; i++) {
        int c = cursor[base_i + i];
        rowptr[base_i + i] = running;
        cursor[base_i + i] = running;
        running += c;
    }
    if (t == 255) rowptr[NN] = running;
}

__global__ void __launch_bounds__(256) scatter_kernel(const int* __restrict__ eidx,
                                                      int* __restrict__ cursor,
                                                      int* __restrict__ perm) {
    int e = blockIdx.x * 256 + threadIdx.x;
    int d_ = eidx[EE + e];
    int pos = atomicAdd(&cursor[d_], 1);
    perm[pos] = e;
}

__global__ void __launch_bounds__(256) deg_hist_kernel(const int* __restrict__ rowptr,
                                                       int* __restrict__ dhist) {
    int n = blockIdx.x * 256 + threadIdx.x;
    int deg = rowptr[n + 1] - rowptr[n];
    atomicAdd(&dhist[min(deg, 63)], 1);
}

__global__ void __launch_bounds__(64) deg_scan_kernel(int* __restrict__ dhist) {
    if (threadIdx.x == 0) {
        int run = 0;
        for (int b = 63; b >= 0; b--) {
            int c = dhist[b];
            dhist[b] = run;
            run += c;
        }
    }
}

__global__ void __launch_bounds__(256) deg_scatter_kernel(const int* __restrict__ rowptr,
                                                          int* __restrict__ dhist,
                                                          int* __restrict__ nodeorder) {
    int n = blockIdx.x * 256 + threadIdx.x;
    int deg = min(rowptr[n + 1] - rowptr[n], 63);
    int pos = atomicAdd(&dhist[deg], 1);
    nodeorder[pos] = n;
}

// ---------------- Node-gather edge kernel: CSR, no atomics ----------------
#define EPB 16

template <int NE>
__device__ __forceinline__ void rbf_gemm(const float* __restrict__ W_rbf, int t,
                                         const float (&rbf_s)[EPB][64],
                                         float bb1, float bb2, float bb3,
                                         float* __restrict__ acc1,
                                         float* __restrict__ acc2,
                                         float* __restrict__ acc3) {
    #pragma unroll
    for (int e = 0; e < NE; e++) { acc1[e] = bb1; acc2[e] = bb2; acc3[e] = bb3; }
    for (int k = 0; k < 64; k++) {
        float w1 = W_rbf[k * 768 + t];
        float w2 = W_rbf[k * 768 + 256 + t];
        float w3 = W_rbf[k * 768 + 512 + t];
        #pragma unroll
        for (int e = 0; e < NE; e++) {
            float r = rbf_s[e][k];
            acc1[e] += r * w1;
            acc2[e] += r * w2;
            acc3[e] += r * w3;
        }
    }
}

__global__ void __launch_bounds__(256) node_gather_kernel(
        const float* __restrict__ rbf,
        const float* __restrict__ W_rbf,
        const float* __restrict__ b_rbf,
        const float* __restrict__ xh,
        const float* __restrict__ vec,
        const float* __restrict__ ev,
        const int* __restrict__ eidx,
        const float* __restrict__ x,
        const int* __restrict__ perm,
        const int* __restrict__ rowptr,
        const int* __restrict__ nodeorder,
        float* __restrict__ x1,
        float* __restrict__ vecacc) {
    int n = nodeorder[blockIdx.x];
    int t = threadIdx.x;
    int beg = rowptr[n], deg = rowptr[n + 1] - beg;

    __shared__ float rbf_s[EPB][64];
    __shared__ int eid_s[EPB], src_s[EPB];
    __shared__ float ev_s[EPB][3];

    float bb1 = b_rbf[t], bb2 = b_rbf[256 + t], bb3 = b_rbf[512 + t];
    float dxa = 0.f, dv0 = 0.f, dv1 = 0.f, dv2 = 0.f;
    float acc1[EPB], acc2[EPB], acc3[EPB];

    for (int b0 = 0; b0 < deg; b0 += EPB) {
        int cnt = min(EPB, deg - b0);
        __syncthreads();
        if (t < cnt) {
            int eid = perm[beg + b0 + t];
            eid_s[t] = eid;
            src_s[t] = eidx[eid];
        }
        __syncthreads();
        #pragma unroll
        for (int i = 0; i < (EPB * 64) / 256; i++) {
            int idx = i * 256 + t;
            int e = idx >> 6, k = idx & 63;
            rbf_s[e][k] = (e < cnt) ? rbf[(long)eid_s[e] * 64 + k] : 0.f;
        }
        if (t < cnt * 3) {
            int e = t / 3, d = t % 3;
            ev_s[e][d] = ev[(long)eid_s[e] * 3 + d];
        }
        __syncthreads();

        if (cnt > 8)      rbf_gemm<16>(W_rbf, t, rbf_s, bb1, bb2, bb3, acc1, acc2, acc3);
        else if (cnt > 4) rbf_gemm<8>(W_rbf, t, rbf_s, bb1, bb2, bb3, acc1, acc2, acc3);
        else              rbf_gemm<4>(W_rbf, t, rbf_s, bb1, bb2, bb3, acc1, acc2, acc3);

        #define EDGE_ACC(e)                                                   \
            {                                                                 \
                int s = src_s[e];                                             \
                const float* xr = xh + (long)s * 768;                         \
                const float* vr = vec + (long)s * 768;                        \
                float m1 = acc1[e] * xr[t];                                   \
                float m2 = acc2[e] * xr[256 + t] * INV_SQRT_3f;               \
                float m3 = acc3[e] * xr[512 + t];                             \
                dxa += m1;                                                    \
                dv0 += (vr[t] * m2       + m3 * ev_s[e][0]) * INV_SQRT_Hf;    \
                dv1 += (vr[256 + t] * m2 + m3 * ev_s[e][1]) * INV_SQRT_Hf;    \
                dv2 += (vr[512 + t] * m2 + m3 * ev_s[e][2]) * INV_SQRT_Hf;    \
            }

        if (cnt == EPB) {
            #pragma unroll 4
            for (int e = 0; e < EPB; e++) EDGE_ACC(e)
        } else {
            for (int e = 0; e < cnt; e++) EDGE_ACC(e)
        }
        #undef EDGE_ACC
    }

    long nb = (long)n * 256 + t;
    x1[nb] = x[nb] + dxa;
    long vb = (long)n * 768 + t;
    vecacc[vb]       = vec[vb]       + dv0;
    vecacc[vb + 256] = vec[vb + 256] + dv1;
    vecacc[vb + 512] = vec[vb + 512] + dv2;
}

// ---------------- vec_dot + vnorm + cat(x, vnorm), split out ----------------
__global__ void __launch_bounds__(256) vdot_cat_kernel(const float* __restrict__ vec1,
                                                       const short* __restrict__ vec2,
                                                       const float* __restrict__ x1,
                                                       float* __restrict__ vdot,
                                                       short* __restrict__ cath,
                                                       short* __restrict__ catl) {
    int idx = blockIdx.x * 256 + threadIdx.x;
    int n = idx >> 8, h = idx & 255;
    float dsum = 0.f, s2 = 0.f;
    #pragma unroll
    for (int d = 0; d < 3; d++) {
        long r = (long)(n * 3 + d) * 256 + h;
        float a = vec1[r];
        float b = b2f(vec2[r]);
        dsum += a * b;
        s2 += b * b;
    }
    vdot[idx] = dsum * INV_SQRT_Hf;
    float xv = x1[idx];
    short hh = f2b(xv);
    cath[(long)n * 512 + h] = hh;
    catl[(long)n * 512 + h] = f2b(xv - b2f(hh));
    float vn = sqrtf(s2 + 1e-8f);
    short vh = f2b(vn);
    cath[(long)n * 512 + 256 + h] = vh;
    catl[(long)n * 512 + 256 + h] = f2b(vn - b2f(vh));
}

// ---------------- x/vec update after xv MLP (IN-PLACE) ----------------
__global__ void __launch_bounds__(256) e4_kernel(float* __restrict__ x1,
                                                 float* __restrict__ vecacc,
                                                 const float* __restrict__ vec1,
                                                 const float* __restrict__ vdot,
                                                 const short* __restrict__ xvh_h,
                                                 const short* __restrict__ xvh_l) {
    int idx = blockIdx.x * 256 + threadIdx.x;
    int n = idx >> 8, h = idx & 255;
    long b0 = (long)n * 768 + h;
    float xv1 = b2f(xvh_h[b0])       + b2f(xvh_l[b0]);
    float xv2 = b2f(xvh_h[b0 + 256]) + b2f(xvh_l[b0 + 256]);
    float xv3 = b2f(xvh_h[b0 + 512]) + b2f(xvh_l[b0 + 512]);
    x1[idx] = x1[idx] + (xv1 + xv2 * vdot[idx]) * INV_SQRT_2f;
    #pragma unroll
    for (int d = 0; d < 3; d++) {
        long r = (long)(n * 3 + d) * 256 + h;
        vecacc[r] = vecacc[r] + xv3 * vec1[r];
    }
}

// ---------------- norm over d + concat(x fp32, norm), split out ----------------
__global__ void __launch_bounds__(256) normcat_kernel(const float* __restrict__ xin,
                                                      const short* __restrict__ w,
                                                      short* __restrict__ cath,
                                                      short* __restrict__ catl,
                                                      int Cx, int C, int shift) {
    int idx = blockIdx.x * 256 + threadIdx.x;
    int cols = 1 << shift;
    int n = idx >> shift, c = idx & (cols - 1);
    float v;
    if (c < Cx) {
        v = xin[(long)n * Cx + c];
    } else {
        int cc = c - Cx;
        float s = 0.f;
        #pragma unroll
        for (int d = 0; d < 3; d++) {
            float a = b2f(w[(long)(n * 3 + d) * C + cc]);
            s += a * a;
        }
        v = sqrtf(s);
    }
    short hh = f2b(v);
    cath[idx] = hh;
    catl[idx] = f2b(v - b2f(hh));
}

// ---------------- gated block 1 epilogue ----------------
__global__ void __launch_bounds__(256) gate1_kernel(const float* __restrict__ h1,
                                                    const short* __restrict__ w2h,
                                                    const short* __restrict__ w2l,
                                                    float* __restrict__ x3,
                                                    short* __restrict__ vecCh,
                                                    short* __restrict__ vecCl) {
    int idx = blockIdx.x * 256 + threadIdx.x;
    int n = idx >> 7, c = idx & 127;
    x3[idx] = ssilu_f(h1[(long)n * 256 + c]);
    float vn = h1[(long)n * 256 + 128 + c];
    #pragma unroll
    for (int d = 0; d < 3; d++) {
        long r = (long)(n * 3 + d) * 128 + c;
        float wv = b2f(w2h[r]) + b2f(w2l[r]);
        float v = vn * wv;
        short hh = f2b(v);
        vecCh[r] = hh;
        vecCl[r] = f2b(v - b2f(hh));
    }
}

// ---------------- vecC @ o2_Wv2 (K=128, Nc=1): one wave per row ----------------
__global__ void __launch_bounds__(256) g12_kernel(const short* __restrict__ vecCh,
                                                  const short* __restrict__ vecCl,
                                                  const float* __restrict__ Wv2,
                                                  float* __restrict__ w4) {
    int row = blockIdx.x * 4 + (threadIdx.x >> 6);
    int lane = threadIdx.x & 63;
    long r0 = (long)row * 128 + lane;
    float v0 = b2f(vecCh[r0]) + b2f(vecCl[r0]);
    float v1 = b2f(vecCh[r0 + 64]) + b2f(vecCl[r0 + 64]);
    float s = v0 * Wv2[lane] + v1 * Wv2[64 + lane];
    #pragma unroll
    for (int off = 32; off > 0; off >>= 1) s += __shfl_down(s, off);
    if (lane == 0) w4[row] = s;
}

// ---------------- final: out[n,d] = (t5[n,:]@Wu2[:,1] + b2[1]) * w4[n,d] ----------
__global__ void __launch_bounds__(256) final_kernel(const float* __restrict__ t5,
                                                    const float* __restrict__ Wu2,
                                                    const float* __restrict__ bu2,
                                                    const float* __restrict__ w4,
                                                    float* __restrict__ out) {
    int n = blockIdx.x * 4 + (threadIdx.x >> 6);
    int lane = threadIdx.x & 63;
    float s = t5[(long)n * 128 + lane] * Wu2[lane * 2 + 1] +
              t5[(long)n * 128 + 64 + lane] * Wu2[(64 + lane) * 2 + 1];
    #pragma unroll
    for (int off = 32; off > 0; off >>= 1) s += __shfl_down(s, off);
    float val = __shfl(s, 0) + bu2[1];
    if (lane < 3) out[(long)n * 3 + lane] = val * w4[(long)n * 3 + lane];
}

extern "C" void kernel_launch(void* const* d_in, const int* in_sizes, int n_in,
                              void* d_out, int out_size, void* d_ws, size_t ws_size,
                              hipStream_t stream) {
    const float* x          = (const float*)d_in[0];
    const float* vec        = (const float*)d_in[1];
    const float* edge_rbf   = (const float*)d_in[2];
    const float* edge_vector= (const float*)d_in[3];
    const float* ln_g       = (const float*)d_in[4];
    const float* ln_b       = (const float*)d_in[5];
    const float* W_x1       = (const float*)d_in[6];
    const float* b_x1       = (const float*)d_in[7];
    const float* W_x2       = (const float*)d_in[8];
    const float* b_x2       = (const float*)d_in[9];
    const float* W_rbf      = (const float*)d_in[10];
    const float* b_rbf      = (const float*)d_in[11];
    const float* W_vp       = (const float*)d_in[12];
    const float* W_xv1      = (const float*)d_in[13];
    const float* b_xv1      = (const float*)d_in[14];
    const float* W_xv2      = (const float*)d_in[15];
    const float* b_xv2      = (const float*)d_in[16];
    const float* o1_Wv1     = (const float*)d_in[17];
    const float* o1_Wv2     = (const float*)d_in[18];
    const float* o1_Wu1     = (const float*)d_in[19];
    const float* o1_bu1     = (const float*)d_in[20];
    const float* o1_Wu2     = (const float*)d_in[21];
    const float* o1_bu2     = (const float*)d_in[22];
    const float* o2_Wv1     = (const float*)d_in[23];
    const float* o2_Wv2     = (const float*)d_in[24];
    const float* o2_Wu1     = (const float*)d_in[25];
    const float* o2_bu1     = (const float*)d_in[26];
    const float* o2_Wu2     = (const float*)d_in[27];
    const float* o2_bu2     = (const float*)d_in[28];
    const int*   edge_index = (const int*)d_in[29];
    float* out = (float*)d_out;
    float* ws  = (float*)d_ws;

    const size_t S = (size_t)NN * 256;
    const size_t Q = S / 4;              // 1,048,576 floats = 4 MiB
    // ---- arena in units of Q; peak 52Q = 208 MiB (proven safe in R2/R3) ----
    float* x1      = ws;                     // Q0-3   (fp32 S)
    float* vecacc  = ws + 4 * Q;             // Q4-15  (fp32 3S)
    short* wtb     = (short*)(ws + 16 * Q);  // Q16-17 weights hi (1,064,960) + lo
    const long WLO = 1064960;                //        lo base offset (shorts)
    // phase 1
    short* xln_h = (short*)(ws + 18 * Q);    // Q18-19
    short* xln_l = (short*)(ws + 20 * Q);    // Q20-21
    short* t1_h  = (short*)(ws + 22 * Q);    // Q22-23
    short* t1_l  = (short*)(ws + 24 * Q);    // Q24-25
    float* xh    = ws + 30 * Q;              // Q30-41 (fp32 3S, dead after gather)
    // phase 2 sort scratch (dead before vdot is written)
    int* rowptr    = (int*)(ws + 48 * Q);    // Q48+ (1.25 MB)
    int* cursor    = rowptr + (NN + 1);
    int* dhist     = cursor + NN;
    int* nodeorder = dhist + 64;
    int* perm      = nodeorder + NN;
    // phase 3
    short* vah   = (short*)(ws + 18 * Q);    // Q18-23 (3S bf16)
    short* val_  = (short*)(ws + 24 * Q);    // Q24-29
    float* vec1  = ws + 30 * Q;              // Q30-41 (fp32 3S, live till e4)
    short* vec2b = (short*)(ws + 42 * Q);    // Q42-47 (bf16 3S)
    float* vdot  = ws + 48 * Q;              // Q48-51 (fp32 S, live till e4)
    short* catb_h = (short*)(ws + 18 * Q);   // Q18-21 (2S bf16; vah dead)
    short* catb_l = (short*)(ws + 22 * Q);   // Q22-25
    short* t2_h  = (short*)(ws + 26 * Q);    // Q26-27
    short* t2_l  = (short*)(ws + 28 * Q);    // Q28-29
    short* xvh_h = (short*)(ws + 18 * Q);    // Q18-23 (catb dead)
    short* xvh_l = (short*)(ws + 42 * Q);    // Q42-47 (vec2 dead)
    // phase 4
    short* vah2  = (short*)(ws + 18 * Q);    // Q18-23
    short* val2  = (short*)(ws + 24 * Q);    // Q24-29
    short* w1b   = (short*)(ws + 30 * Q);    // Q30-35 (bf16 3S)
    short* w2_h  = (short*)(ws + 36 * Q);    // Q36-38 (1.5S bf16)
    short* w2_l  = (short*)(ws + 39 * Q);    // Q39-41
    short* cat2_h = (short*)(ws + 42 * Q);   // Q42-45 (2S bf16)
    short* cat2_l = (short*)(ws + 46 * Q);   // Q46-49
    short* t4_h  = (short*)(ws + 18 * Q);    // Q18-19
    short* t4_l  = (short*)(ws + 20 * Q);    // Q20-21
    float* h1    = ws + 22 * Q;              // Q22-25 (fp32 S)
    float* x3    = ws + 26 * Q;              // Q26-27 (fp32 S/2)
    short* vecC_h = (short*)(ws + 28 * Q);   // Q28-30 (1.5S bf16)
    short* vecC_l = (short*)(ws + 31 * Q);   // Q31-33
    // phase 5
    short* w3b   = (short*)(ws + 34 * Q);    // Q34-36 (1.5S bf16)
    float* w4    = ws + 37 * Q;              // Q37 (3N fp32)
    short* cat3_h = (short*)(ws + 38 * Q);   // Q38-39 (S bf16)
    short* cat3_l = (short*)(ws + 40 * Q);   // Q40-41
    float* t5    = ws + 42 * Q;              // Q42-43 (fp32 S/2)

    // weight hi/lo offsets (shorts)
    short* WT_x1    = wtb;
    short* WT_x2    = wtb + 65536;
    short* WT_vp    = wtb + 262144;
    short* WT_xv1   = wtb + 393216;
    short* WT_xv2   = wtb + 524288;
    short* WT_o1Wv1 = wtb + 720896;
    short* WT_o1Wv2 = wtb + 786432;
    short* WT_o1Wu1 = wtb + 819200;
    short* WT_o1Wu2 = wtb + 950272;
    short* WT_o2Wv1 = wtb + 1015808;
    short* WT_o2Wu1 = wtb + 1032192;

    // Phase 0: weight transpose + split
    wt_split_kernel<<<65536 / 256, 256, 0, stream>>>(W_x1, WT_x1, WT_x1 + WLO, 256, 256);
    wt_split_kernel<<<196608 / 256, 256, 0, stream>>>(W_x2, WT_x2, WT_x2 + WLO, 256, 768);
    wt_split_kernel<<<131072 / 256, 256, 0, stream>>>(W_vp, WT_vp, WT_vp + WLO, 256, 512);
    wt_split_kernel<<<131072 / 256, 256, 0, stream>>>(W_xv1, WT_xv1, WT_xv1 + WLO, 512, 256);
    wt_split_kernel<<<196608 / 256, 256, 0, stream>>>(W_xv2, WT_xv2, WT_xv2 + WLO, 256, 768);
    wt_split_kernel<<<65536 / 256, 256, 0, stream>>>(o1_Wv1, WT_o1Wv1, WT_o1Wv1 + WLO, 256, 256);
    wt_split_kernel<<<32768 / 256, 256, 0, stream>>>(o1_Wv2, WT_o1Wv2, WT_o1Wv2 + WLO, 256, 128);
    wt_split_kernel<<<131072 / 256, 256, 0, stream>>>(o1_Wu1, WT_o1Wu1, WT_o1Wu1 + WLO, 512, 256);
    wt_split_kernel<<<65536 / 256, 256, 0, stream>>>(o1_Wu2, WT_o1Wu2, WT_o1Wu2 + WLO, 256, 256);
    wt_split_kernel<<<16384 / 256, 256, 0, stream>>>(o2_Wv1, WT_o2Wv1, WT_o2Wv1 + WLO, 128, 128);
    wt_split_kernel<<<32768 / 256, 256, 0, stream>>>(o2_Wu1, WT_o2Wu1, WT_o2Wu1 + WLO, 256, 128);

    // Phase 1: node MLP
    ln_kernel<<<NN, 256, 0, stream>>>(x, ln_g, ln_b, xln_h, xln_l);
    mfma_gemm<<<dim3(NN / 64, 4), 256, 0, stream>>>(xln_h, xln_l, WT_x1, WT_x1 + WLO,
                                                    b_x1, t1_h, t1_l, NN, 256, 256, 1);
    mfma_gemm<<<dim3(NN / 64, 12), 256, 0, stream>>>(t1_h, t1_l, WT_x2, WT_x2 + WLO,
                                                     b_x2, xh, nullptr, NN, 256, 768, 0);

    // Phase 2: sort edges by dst; node order by desc degree; CSR gather (no atomics)
    zero_kernel<<<(NN + 64 + 255) / 256, 256, 0, stream>>>(cursor, NN + 64);
    hist_kernel<<<EE / 256, 256, 0, stream>>>(edge_index, cursor);
    scan_kernel<<<1, 256, 0, stream>>>(cursor, rowptr);
    scatter_kernel<<<EE / 256, 256, 0, stream>>>(edge_index, cursor, perm);
    deg_hist_kernel<<<NN / 256, 256, 0, stream>>>(rowptr, dhist);
    deg_scan_kernel<<<1, 64, 0, stream>>>(dhist);
    deg_scatter_kernel<<<NN / 256, 256, 0, stream>>>(rowptr, dhist, nodeorder);
    node_gather_kernel<<<NN, 256, 0, stream>>>(edge_rbf, W_rbf, b_rbf, xh, vec,
                                               edge_vector, edge_index, x,
                                               perm, rowptr, nodeorder, x1, vecacc);

    // Phase 3: vp, vdot/vnorm, xv MLP, in-place updates
    split4_kernel<<<3 * S / 1024, 256, 0, stream>>>(vecacc, vah, val_);
    mfma_gemm<<<dim3(3 * NN / 64, 4), 256, 0, stream>>>(vah, val_, WT_vp, WT_vp + WLO,
                                                        nullptr, vec1, nullptr,
                                                        3 * NN, 256, 256, 0);
    mfma_gemm<<<dim3(3 * NN / 64, 4), 256, 0, stream>>>(vah, val_, WT_vp + 65536,
                                                        WT_vp + WLO + 65536,
                                                        nullptr, vec2b, nullptr,
                                                        3 * NN, 256, 256, 2);
    vdot_cat_kernel<<<NN, 256, 0, stream>>>(vec1, vec2b, x1, vdot, catb_h, catb_l);
    mfma_gemm<<<dim3(NN / 64, 4), 256, 0, stream>>>(catb_h, catb_l, WT_xv1, WT_xv1 + WLO,
                                                    b_xv1, t2_h, t2_l, NN, 512, 256, 1);
    mfma_gemm<<<dim3(NN / 64, 12), 256, 0, stream>>>(t2_h, t2_l, WT_xv2, WT_xv2 + WLO,
                                                     b_xv2, xvh_h, xvh_l, NN, 256, 768, 0);
    e4_kernel<<<NN, 256, 0, stream>>>(x1, vecacc, vec1, vdot, xvh_h, xvh_l);

    // Phase 4: gated equivariant block 1
    split4_kernel<<<3 * S / 1024, 256, 0, stream>>>(vecacc, vah2, val2);
    mfma_gemm<<<dim3(3 * NN / 64, 4), 256, 0, stream>>>(vah2, val2, WT_o1Wv1, WT_o1Wv1 + WLO,
                                                        nullptr, w1b, nullptr,
                                                        3 * NN, 256, 256, 2);
    mfma_gemm<<<dim3(3 * NN / 64, 2), 256, 0, stream>>>(vah2, val2, WT_o1Wv2, WT_o1Wv2 + WLO,
                                                        nullptr, w2_h, w2_l,
                                                        3 * NN, 256, 128, 0);
    normcat_kernel<<<NN * 512 / 256, 256, 0, stream>>>(x1, w1b, cat2_h, cat2_l, 256, 256, 9);
    mfma_gemm<<<dim3(NN / 64, 4), 256, 0, stream>>>(cat2_h, cat2_l, WT_o1Wu1, WT_o1Wu1 + WLO,
                                                    o1_bu1, t4_h, t4_l, NN, 512, 256, 1);
    mfma_gemm<<<dim3(NN / 64, 4), 256, 0, stream>>>(t4_h, t4_l, WT_o1Wu2, WT_o1Wu2 + WLO,
                                                    o1_bu2, h1, nullptr, NN, 256, 256, 0);
    gate1_kernel<<<NN * 128 / 256, 256, 0, stream>>>(h1, w2_h, w2_l, x3, vecC_h, vecC_l);

    // Phase 5: gated equivariant block 2 + output
    mfma_gemm<<<dim3(3 * NN / 64, 2), 256, 0, stream>>>(vecC_h, vecC_l, WT_o2Wv1,
                                                        WT_o2Wv1 + WLO, nullptr,
                                                        w3b, nullptr, 3 * NN, 128, 128, 2);
    g12_kernel<<<3 * NN / 4, 256, 0, stream>>>(vecC_h, vecC_l, o2_Wv2, w4);
    normcat_kernel<<<NN * 256 / 256, 256, 0, stream>>>(x3, w3b, cat3_h, cat3_l, 128, 128, 8);
    mfma_gemm<<<dim3(NN / 64, 2), 256, 0, stream>>>(cat3_h, cat3_l, WT_o2Wu1, WT_o2Wu1 + WLO,
                                                    o2_bu1, t5, nullptr, NN, 256, 128, 1);
    final_kernel<<<NN / 4, 256, 0, stream>>>(t5, o2_Wu2, o2_bu2, w4, out);
}

// Round 7
// 1680.609 us; speedup vs baseline: 1.1852x; 1.1852x over previous
//
#include <hip/hip_runtime.h>
#include <math.h>

#define NN 16384
#define EE 262144
#define HH 256

#define INV_SQRT_3f 0.57735026918962576f
#define INV_SQRT_Hf 0.0625f
#define INV_SQRT_2f 0.70710678118654752f
#define SSILU_SCALE 1.6666666666666667f

typedef __attribute__((ext_vector_type(8))) short bf16x8;
typedef __attribute__((ext_vector_type(4))) float f32x4;

__device__ __forceinline__ float ssilu_f(float v) {
    return v * (1.0f / (1.0f + __expf(-v))) * SSILU_SCALE;
}
__device__ __forceinline__ float b2f(short s) {
    unsigned int u = ((unsigned int)(unsigned short)s) << 16;
    return __uint_as_float(u);
}
__device__ __forceinline__ short f2b(float f) {
    unsigned int u = __float_as_uint(f);
    unsigned int r = (u + 0x7fff + ((u >> 16) & 1)) >> 16;
    return (short)r;
}

// ---------------- LayerNorm: one block per row, split-bf16 out ----------------
__global__ void __launch_bounds__(256) ln_kernel(const float* __restrict__ x,
                                                 const float* __restrict__ g,
                                                 const float* __restrict__ b,
                                                 short* __restrict__ oh,
                                                 short* __restrict__ ol) {
    int n = blockIdx.x;
    int t = threadIdx.x;
    float v = x[(long)n * HH + t];
    float s = v, s2 = v * v;
    #pragma unroll
    for (int off = 32; off > 0; off >>= 1) {
        s  += __shfl_down(s, off);
        s2 += __shfl_down(s2, off);
    }
    __shared__ float red[8];
    int wave = t >> 6, lane = t & 63;
    if (lane == 0) { red[wave] = s; red[4 + wave] = s2; }
    __syncthreads();
    __shared__ float mr[2];
    if (t == 0) {
        float ts = red[0] + red[1] + red[2] + red[3];
        float ts2 = red[4] + red[5] + red[6] + red[7];
        float mean = ts * (1.0f / HH);
        float var = ts2 * (1.0f / HH) - mean * mean;
        mr[0] = mean;
        mr[1] = rsqrtf(var + 1e-5f);
    }
    __syncthreads();
    float o = (v - mr[0]) * mr[1] * g[t] + b[t];
    short hh = f2b(o);
    oh[(long)n * HH + t] = hh;
    ol[(long)n * HH + t] = f2b(o - b2f(hh));
}

// ---- ALL weight transposes + hi/lo splits in ONE kernel ----
struct WtArgs {
    const float* W[11];
    int K[11];
    int N[11];
    int off[12];   // cumulative element offsets; off[11] = total
};

__global__ void __launch_bounds__(256) wt_split_all(WtArgs a,
                                                    short* __restrict__ WTh,
                                                    short* __restrict__ WTl) {
    int idx = blockIdx.x * 256 + threadIdx.x;
    int s = 0;
    #pragma unroll
    for (int i = 1; i < 11; i++) s += (idx >= a.off[i]) ? 1 : 0;
    int local = idx - a.off[s];
    int K = a.K[s], N = a.N[s];
    int k = local / N, n = local - k * N;
    float w = a.W[s][local];
    short hh = f2b(w);
    long o = (long)a.off[s] + (long)n * K + k;
    WTh[o] = hh;
    WTl[o] = f2b(w - b2f(hh));
}

// ---- fp32 -> hi/lo split (count % 1024 == 0) ----
__global__ void __launch_bounds__(256) split4_kernel(const float* __restrict__ in,
                                                     short* __restrict__ h,
                                                     short* __restrict__ l) {
    long i = ((long)blockIdx.x * 256 + threadIdx.x) * 4;
    float4 v = *(const float4*)(in + i);
    short4 oh, ol;
    oh.x = f2b(v.x); ol.x = f2b(v.x - b2f(oh.x));
    oh.y = f2b(v.y); ol.y = f2b(v.y - b2f(oh.y));
    oh.z = f2b(v.z); ol.z = f2b(v.z - b2f(oh.z));
    oh.w = f2b(v.w); ol.w = f2b(v.w - b2f(oh.w));
    *(short4*)(h + i) = oh;
    *(short4*)(l + i) = ol;
}

// ---- split-bf16 MFMA GEMM v2: C = (Ah+Al)(M,K) @ (Wh+Wl)^T(N,K) [+bias][ssilu]
// C ~= Ah@Wh + Al@Wh + Ah@Wl. block = 4 waves, 128 rows x 64 cols;
// wave = 32 rows (2 frags) x 64 cols (4 tiles) = 8 acc tiles.
// K-loop chunk 32 with register prefetch of next chunk.
// M%128==0, N%64==0, K%32==0. out: Cl!=null -> split; act&2 -> bf16; else fp32.
__global__ void __launch_bounds__(256) mfma_gemm(const short* __restrict__ Ah,
                                                 const short* __restrict__ Al,
                                                 const short* __restrict__ Wh,
                                                 const short* __restrict__ Wl,
                                                 const float* __restrict__ bias,
                                                 void* __restrict__ Ch,
                                                 short* __restrict__ Cl,
                                                 int M, int K, int N, int act) {
    int tid = threadIdx.x;
    int wave = tid >> 6, lane = tid & 63;
    int quad = lane >> 4, l16 = lane & 15;
    long bm = (long)blockIdx.x * 128 + wave * 32;
    long bn = (long)blockIdx.y * 64;
    long a0 = (bm + l16) * K + quad * 8;
    long a1 = a0 + (long)16 * K;
    long w0 = (bn + l16) * K + quad * 8;

    f32x4 acc[2][4];
    #pragma unroll
    for (int f = 0; f < 2; f++)
        #pragma unroll
        for (int t = 0; t < 4; t++) acc[f][t] = (f32x4){0.f, 0.f, 0.f, 0.f};

    bf16x8 cah[2], cal[2], cbh[4], cbl[4];
    cah[0] = *(const bf16x8*)(Ah + a0);
    cah[1] = *(const bf16x8*)(Ah + a1);
    cal[0] = *(const bf16x8*)(Al + a0);
    cal[1] = *(const bf16x8*)(Al + a1);
    #pragma unroll
    for (int t = 0; t < 4; t++) {
        long wo = w0 + (long)t * 16 * K;
        cbh[t] = *(const bf16x8*)(Wh + wo);
        cbl[t] = *(const bf16x8*)(Wl + wo);
    }

    for (int k0 = 0; k0 < K; k0 += 32) {
        int k1 = k0 + 32;
        bf16x8 nah[2], nal[2], nbh[4], nbl[4];
        if (k1 < K) {
            nah[0] = *(const bf16x8*)(Ah + a0 + k1);
            nah[1] = *(const bf16x8*)(Ah + a1 + k1);
            nal[0] = *(const bf16x8*)(Al + a0 + k1);
            nal[1] = *(const bf16x8*)(Al + a1 + k1);
            #pragma unroll
            for (int t = 0; t < 4; t++) {
                long wo = w0 + (long)t * 16 * K + k1;
                nbh[t] = *(const bf16x8*)(Wh + wo);
                nbl[t] = *(const bf16x8*)(Wl + wo);
            }
        }
        #pragma unroll
        for (int t = 0; t < 4; t++) {
            #pragma unroll
            for (int f = 0; f < 2; f++) {
                acc[f][t] = __builtin_amdgcn_mfma_f32_16x16x32_bf16(cah[f], cbh[t], acc[f][t], 0, 0, 0);
                acc[f][t] = __builtin_amdgcn_mfma_f32_16x16x32_bf16(cal[f], cbh[t], acc[f][t], 0, 0, 0);
                acc[f][t] = __builtin_amdgcn_mfma_f32_16x16x32_bf16(cah[f], cbl[t], acc[f][t], 0, 0, 0);
            }
        }
        if (k1 < K) {
            cah[0] = nah[0]; cah[1] = nah[1];
            cal[0] = nal[0]; cal[1] = nal[1];
            #pragma unroll
            for (int t = 0; t < 4; t++) { cbh[t] = nbh[t]; cbl[t] = nbl[t]; }
        }
    }

    #pragma unroll
    for (int f = 0; f < 2; f++) {
        long row0 = bm + f * 16 + quad * 4;
        #pragma unroll
        for (int t = 0; t < 4; t++) {
            long col = bn + t * 16 + l16;
            float bv = bias ? bias[col] : 0.f;
            #pragma unroll
            for (int r = 0; r < 4; r++) {
                float v = acc[f][t][r] + bv;
                if (act & 1) v = ssilu_f(v);
                long idx = (row0 + r) * N + col;
                if (Cl) {
                    short hh = f2b(v);
                    ((short*)Ch)[idx] = hh;
                    Cl[idx] = f2b(v - b2f(hh));
                } else if (act & 2) {
                    ((short*)Ch)[idx] = f2b(v);
                } else {
                    ((float*)Ch)[idx] = v;
                }
            }
        }
    }
}

// ---------------- edge sort (counting sort by dst) ----------------
__global__ void __launch_bounds__(256) zero_kernel(int* __restrict__ p, int n) {
    int i = blockIdx.x * 256 + threadIdx.x;
    if (i < n) p[i] = 0;
}

__global__ void __launch_bounds__(256) hist_kernel(const int* __restrict__ eidx,
                                                   int* __restrict__ cnt) {
    int e = blockIdx.x * 256 + threadIdx.x;
    atomicAdd(&cnt[eidx[EE + e]], 1);
}

__global__ void __launch_bounds__(256) scan_kernel(int* __restrict__ cursor,
                                                   int* __restrict__ rowptr) {
    int t = threadIdx.x;
    int base_i = t * 64;
    int tsum = 0;
    for (int i = 0; i < 64; i++) tsum += cursor[base_i + i];
    __shared__ int ls[256];
    ls[t] = tsum;
    __syncthreads();
    for (int off = 1; off < 256; off <<= 1) {
        int v = (t >= off) ? ls[t - off] : 0;
        __syncthreads();
        ls[t] += v;
        __syncthreads();
    }
    int running = ls[t] - tsum;
    for (int i = 0; i < 64; i++) {
        int c = cursor[base_i + i];
        rowptr[base_i + i] = running;
        cursor[base_i + i] = running;
        running += c;
    }
    if (t == 255) rowptr[NN] = running;
}

__global__ void __launch_bounds__(256) scatter_kernel(const int* __restrict__ eidx,
                                                      int* __restrict__ cursor,
                                                      int* __restrict__ perm) {
    int e = blockIdx.x * 256 + threadIdx.x;
    int d_ = eidx[EE + e];
    int pos = atomicAdd(&cursor[d_], 1);
    perm[pos] = e;
}

__global__ void __launch_bounds__(256) deg_hist_kernel(const int* __restrict__ rowptr,
                                                       int* __restrict__ dhist) {
    int n = blockIdx.x * 256 + threadIdx.x;
    int deg = rowptr[n + 1] - rowptr[n];
    atomicAdd(&dhist[min(deg, 63)], 1);
}

__global__ void __launch_bounds__(64) deg_scan_kernel(int* __restrict__ dhist) {
    if (threadIdx.x == 0) {
        int run = 0;
        for (int b = 63; b >= 0; b--) {
            int c = dhist[b];
            dhist[b] = run;
            run += c;
        }
    }
}

__global__ void __launch_bounds__(256) deg_scatter_kernel(const int* __restrict__ rowptr,
                                                          int* __restrict__ dhist,
                                                          int* __restrict__ nodeorder) {
    int n = blockIdx.x * 256 + threadIdx.x;
    int deg = min(rowptr[n + 1] - rowptr[n], 63);
    int pos = atomicAdd(&dhist[deg], 1);
    nodeorder[pos] = n;
}

// ---------------- Node-gather edge kernel: CSR, no atomics ----------------
// Epilogue also emits the hi/lo split of vecacc (feeds phase-3 GEMMs directly).
#define EPB 16

template <int NE>
__device__ __forceinline__ void rbf_gemm(const float* __restrict__ W_rbf, int t,
                                         const float (&rbf_s)[EPB][64],
                                         float bb1, float bb2, float bb3,
                                         float* __restrict__ acc1,
                                         float* __restrict__ acc2,
                                         float* __restrict__ acc3) {
    #pragma unroll
    for (int e = 0; e < NE; e++) { acc1[e] = bb1; acc2[e] = bb2; acc3[e] = bb3; }
    for (int k = 0; k < 64; k++) {
        float w1 = W_rbf[k * 768 + t];
        float w2 = W_rbf[k * 768 + 256 + t];
        float w3 = W_rbf[k * 768 + 512 + t];
        #pragma unroll
        for (int e = 0; e < NE; e++) {
            float r = rbf_s[e][k];
            acc1[e] += r * w1;
            acc2[e] += r * w2;
            acc3[e] += r * w3;
        }
    }
}

__global__ void __launch_bounds__(256) node_gather_kernel(
        const float* __restrict__ rbf,
        const float* __restrict__ W_rbf,
        const float* __restrict__ b_rbf,
        const float* __restrict__ xh,
        const float* __restrict__ vec,
        const float* __restrict__ ev,
        const int* __restrict__ eidx,
        const float* __restrict__ x,
        const int* __restrict__ perm,
        const int* __restrict__ rowptr,
        const int* __restrict__ nodeorder,
        float* __restrict__ x1,
        float* __restrict__ vecacc,
        short* __restrict__ vah,
        short* __restrict__ val) {
    int n = nodeorder[blockIdx.x];
    int t = threadIdx.x;
    int beg = rowptr[n], deg = rowptr[n + 1] - beg;

    __shared__ float rbf_s[EPB][64];
    __shared__ int eid_s[EPB], src_s[EPB];
    __shared__ float ev_s[EPB][3];

    float bb1 = b_rbf[t], bb2 = b_rbf[256 + t], bb3 = b_rbf[512 + t];
    float dxa = 0.f, dv0 = 0.f, dv1 = 0.f, dv2 = 0.f;
    float acc1[EPB], acc2[EPB], acc3[EPB];

    for (int b0 = 0; b0 < deg; b0 += EPB) {
        int cnt = min(EPB, deg - b0);
        __syncthreads();
        if (t < cnt) {
            int eid = perm[beg + b0 + t];
            eid_s[t] = eid;
            src_s[t] = eidx[eid];
        }
        __syncthreads();
        #pragma unroll
        for (int i = 0; i < (EPB * 64) / 256; i++) {
            int idx = i * 256 + t;
            int e = idx >> 6, k = idx & 63;
            rbf_s[e][k] = (e < cnt) ? rbf[(long)eid_s[e] * 64 + k] : 0.f;
        }
        if (t < cnt * 3) {
            int e = t / 3, d = t % 3;
            ev_s[e][d] = ev[(long)eid_s[e] * 3 + d];
        }
        __syncthreads();

        if (cnt > 8)      rbf_gemm<16>(W_rbf, t, rbf_s, bb1, bb2, bb3, acc1, acc2, acc3);
        else if (cnt > 4) rbf_gemm<8>(W_rbf, t, rbf_s, bb1, bb2, bb3, acc1, acc2, acc3);
        else              rbf_gemm<4>(W_rbf, t, rbf_s, bb1, bb2, bb3, acc1, acc2, acc3);

        #define EDGE_ACC(e)                                                   \
            {                                                                 \
                int s = src_s[e];                                             \
                const float* xr = xh + (long)s * 768;                         \
                const float* vr = vec + (long)s * 768;                        \
                float m1 = acc1[e] * xr[t];                                   \
                float m2 = acc2[e] * xr[256 + t] * INV_SQRT_3f;               \
                float m3 = acc3[e] * xr[512 + t];                             \
                dxa += m1;                                                    \
                dv0 += (vr[t] * m2       + m3 * ev_s[e][0]) * INV_SQRT_Hf;    \
                dv1 += (vr[256 + t] * m2 + m3 * ev_s[e][1]) * INV_SQRT_Hf;    \
                dv2 += (vr[512 + t] * m2 + m3 * ev_s[e][2]) * INV_SQRT_Hf;    \
            }

        if (cnt == EPB) {
            #pragma unroll 4
            for (int e = 0; e < EPB; e++) EDGE_ACC(e)
        } else {
            for (int e = 0; e < cnt; e++) EDGE_ACC(e)
        }
        #undef EDGE_ACC
    }

    long nb = (long)n * 256 + t;
    x1[nb] = x[nb] + dxa;
    long vb = (long)n * 768 + t;
    float vv0 = vec[vb] + dv0;
    float vv1 = vec[vb + 256] + dv1;
    float vv2 = vec[vb + 512] + dv2;
    vecacc[vb]       = vv0;
    vecacc[vb + 256] = vv1;
    vecacc[vb + 512] = vv2;
    short h0 = f2b(vv0), h1 = f2b(vv1), h2 = f2b(vv2);
    vah[vb]       = h0;  val[vb]       = f2b(vv0 - b2f(h0));
    vah[vb + 256] = h1;  val[vb + 256] = f2b(vv1 - b2f(h1));
    vah[vb + 512] = h2;  val[vb + 512] = f2b(vv2 - b2f(h2));
}

// ---------------- vec_dot + vnorm + cat(x, vnorm), split out ----------------
__global__ void __launch_bounds__(256) vdot_cat_kernel(const float* __restrict__ vec1,
                                                       const short* __restrict__ vec2,
                                                       const float* __restrict__ x1,
                                                       float* __restrict__ vdot,
                                                       short* __restrict__ cath,
                                                       short* __restrict__ catl) {
    int idx = blockIdx.x * 256 + threadIdx.x;
    int n = idx >> 8, h = idx & 255;
    float dsum = 0.f, s2 = 0.f;
    #pragma unroll
    for (int d = 0; d < 3; d++) {
        long r = (long)(n * 3 + d) * 256 + h;
        float a = vec1[r];
        float b = b2f(vec2[r]);
        dsum += a * b;
        s2 += b * b;
    }
    vdot[idx] = dsum * INV_SQRT_Hf;
    float xv = x1[idx];
    short hh = f2b(xv);
    cath[(long)n * 512 + h] = hh;
    catl[(long)n * 512 + h] = f2b(xv - b2f(hh));
    float vn = sqrtf(s2 + 1e-8f);
    short vh = f2b(vn);
    cath[(long)n * 512 + 256 + h] = vh;
    catl[(long)n * 512 + 256 + h] = f2b(vn - b2f(vh));
}

// ---------------- x/vec update after xv MLP (IN-PLACE) ----------------
__global__ void __launch_bounds__(256) e4_kernel(float* __restrict__ x1,
                                                 float* __restrict__ vecacc,
                                                 const float* __restrict__ vec1,
                                                 const float* __restrict__ vdot,
                                                 const short* __restrict__ xvh_h,
                                                 const short* __restrict__ xvh_l) {
    int idx = blockIdx.x * 256 + threadIdx.x;
    int n = idx >> 8, h = idx & 255;
    long b0 = (long)n * 768 + h;
    float xv1 = b2f(xvh_h[b0])       + b2f(xvh_l[b0]);
    float xv2 = b2f(xvh_h[b0 + 256]) + b2f(xvh_l[b0 + 256]);
    float xv3 = b2f(xvh_h[b0 + 512]) + b2f(xvh_l[b0 + 512]);
    x1[idx] = x1[idx] + (xv1 + xv2 * vdot[idx]) * INV_SQRT_2f;
    #pragma unroll
    for (int d = 0; d < 3; d++) {
        long r = (long)(n * 3 + d) * 256 + h;
        vecacc[r] = vecacc[r] + xv3 * vec1[r];
    }
}

// ---------------- norm over d + concat(x fp32, norm), split out ----------------
__global__ void __launch_bounds__(256) normcat_kernel(const float* __restrict__ xin,
                                                      const short* __restrict__ w,
                                                      short* __restrict__ cath,
                                                      short* __restrict__ catl,
                                                      int Cx, int C, int shift) {
    int idx = blockIdx.x * 256 + threadIdx.x;
    int cols = 1 << shift;
    int n = idx >> shift, c = idx & (cols - 1);
    float v;
    if (c < Cx) {
        v = xin[(long)n * Cx + c];
    } else {
        int cc = c - Cx;
        float s = 0.f;
        #pragma unroll
        for (int d = 0; d < 3; d++) {
            float a = b2f(w[(long)(n * 3 + d) * C + cc]);
            s += a * a;
        }
        v = sqrtf(s);
    }
    short hh = f2b(v);
    cath[idx] = hh;
    catl[idx] = f2b(v - b2f(hh));
}

// ---------------- gated block 1 epilogue ----------------
__global__ void __launch_bounds__(256) gate1_kernel(const float* __restrict__ h1,
                                                    const short* __restrict__ w2h,
                                                    const short* __restrict__ w2l,
                                                    float* __restrict__ x3,
                                                    short* __restrict__ vecCh,
                                                    short* __restrict__ vecCl) {
    int idx = blockIdx.x * 256 + threadIdx.x;
    int n = idx >> 7, c = idx & 127;
    x3[idx] = ssilu_f(h1[(long)n * 256 + c]);
    float vn = h1[(long)n * 256 + 128 + c];
    #pragma unroll
    for (int d = 0; d < 3; d++) {
        long r = (long)(n * 3 + d) * 128 + c;
        float wv = b2f(w2h[r]) + b2f(w2l[r]);
        float v = vn * wv;
        short hh = f2b(v);
        vecCh[r] = hh;
        vecCl[r] = f2b(v - b2f(hh));
    }
}

// ---------------- vecC @ o2_Wv2 (K=128, Nc=1): one wave per row ----------------
__global__ void __launch_bounds__(256) g12_kernel(const short* __restrict__ vecCh,
                                                  const short* __restrict__ vecCl,
                                                  const float* __restrict__ Wv2,
                                                  float* __restrict__ w4) {
    int row = blockIdx.x * 4 + (threadIdx.x >> 6);
    int lane = threadIdx.x & 63;
    long r0 = (long)row * 128 + lane;
    float v0 = b2f(vecCh[r0]) + b2f(vecCl[r0]);
    float v1 = b2f(vecCh[r0 + 64]) + b2f(vecCl[r0 + 64]);
    float s = v0 * Wv2[lane] + v1 * Wv2[64 + lane];
    #pragma unroll
    for (int off = 32; off > 0; off >>= 1) s += __shfl_down(s, off);
    if (lane == 0) w4[row] = s;
}

// ---------------- final: out[n,d] = (t5[n,:]@Wu2[:,1] + b2[1]) * w4[n,d] ----------
__global__ void __launch_bounds__(256) final_kernel(const float* __restrict__ t5,
                                                    const float* __restrict__ Wu2,
                                                    const float* __restrict__ bu2,
                                                    const float* __restrict__ w4,
                                                    float* __restrict__ out) {
    int n = blockIdx.x * 4 + (threadIdx.x >> 6);
    int lane = threadIdx.x & 63;
    float s = t5[(long)n * 128 + lane] * Wu2[lane * 2 + 1] +
              t5[(long)n * 128 + 64 + lane] * Wu2[(64 + lane) * 2 + 1];
    #pragma unroll
    for (int off = 32; off > 0; off >>= 1) s += __shfl_down(s, off);
    float val = __shfl(s, 0) + bu2[1];
    if (lane < 3) out[(long)n * 3 + lane] = val * w4[(long)n * 3 + lane];
}

extern "C" void kernel_launch(void* const* d_in, const int* in_sizes, int n_in,
                              void* d_out, int out_size, void* d_ws, size_t ws_size,
                              hipStream_t stream) {
    const float* x          = (const float*)d_in[0];
    const float* vec        = (const float*)d_in[1];
    const float* edge_rbf   = (const float*)d_in[2];
    const float* edge_vector= (const float*)d_in[3];
    const float* ln_g       = (const float*)d_in[4];
    const float* ln_b       = (const float*)d_in[5];
    const float* W_x1       = (const float*)d_in[6];
    const float* b_x1       = (const float*)d_in[7];
    const float* W_x2       = (const float*)d_in[8];
    const float* b_x2       = (const float*)d_in[9];
    const float* W_rbf      = (const float*)d_in[10];
    const float* b_rbf      = (const float*)d_in[11];
    const float* W_vp       = (const float*)d_in[12];
    const float* W_xv1      = (const float*)d_in[13];
    const float* b_xv1      = (const float*)d_in[14];
    const float* W_xv2      = (const float*)d_in[15];
    const float* b_xv2      = (const float*)d_in[16];
    const float* o1_Wv1     = (const float*)d_in[17];
    const float* o1_Wv2     = (const float*)d_in[18];
    const float* o1_Wu1     = (const float*)d_in[19];
    const float* o1_bu1     = (const float*)d_in[20];
    const float* o1_Wu2     = (const float*)d_in[21];
    const float* o1_bu2     = (const float*)d_in[22];
    const float* o2_Wv1     = (const float*)d_in[23];
    const float* o2_Wv2     = (const float*)d_in[24];
    const float* o2_Wu1     = (const float*)d_in[25];
    const float* o2_bu1     = (const float*)d_in[26];
    const float* o2_Wu2     = (const float*)d_in[27];
    const float* o2_bu2     = (const float*)d_in[28];
    const int*   edge_index = (const int*)d_in[29];
    float* out = (float*)d_out;
    float* ws  = (float*)d_ws;

    const size_t S = (size_t)NN * 256;
    const size_t Q = S / 4;              // 1,048,576 floats = 4 MiB
    // ---- arena in units of Q; peak 52Q = 208 MiB (proven safe) ----
    float* x1      = ws;                     // Q0-3   (fp32 S)
    float* vecacc  = ws + 4 * Q;             // Q4-15  (fp32 3S)
    short* wtb     = (short*)(ws + 16 * Q);  // Q16-17 weights hi + lo
    const long WLO = 1064960;
    // phase 1
    short* xln_h = (short*)(ws + 18 * Q);    // Q18-19 (dead after t1 gemm)
    short* xln_l = (short*)(ws + 20 * Q);    // Q20-21
    short* t1_h  = (short*)(ws + 22 * Q);    // Q22-23 (dead after xh gemm)
    short* t1_l  = (short*)(ws + 24 * Q);    // Q24-25
    float* xh    = ws + 30 * Q;              // Q30-41 (fp32 3S, dead after gather)
    // phase 2 sort scratch (dead before vdot is written)
    int* rowptr    = (int*)(ws + 48 * Q);
    int* cursor    = rowptr + (NN + 1);
    int* dhist     = cursor + NN;
    int* nodeorder = dhist + 64;
    int* perm      = nodeorder + NN;
    // phase 3 (vah/val_ now written by node_gather directly)
    short* vah   = (short*)(ws + 18 * Q);    // Q18-23 (3S bf16)
    short* val_  = (short*)(ws + 24 * Q);    // Q24-29
    float* vec1  = ws + 30 * Q;              // Q30-41 (fp32 3S, live till e4)
    short* vec2b = (short*)(ws + 42 * Q);    // Q42-47 (bf16 3S)
    float* vdot  = ws + 48 * Q;              // Q48-51 (fp32 S, live till e4)
    short* catb_h = (short*)(ws + 18 * Q);   // Q18-21 (vah dead after vp gemms)
    short* catb_l = (short*)(ws + 22 * Q);   // Q22-25
    short* t2_h  = (short*)(ws + 26 * Q);    // Q26-27
    short* t2_l  = (short*)(ws + 28 * Q);    // Q28-29
    short* xvh_h = (short*)(ws + 18 * Q);    // Q18-23 (catb dead)
    short* xvh_l = (short*)(ws + 42 * Q);    // Q42-47 (vec2 dead)
    // phase 4
    short* vah2  = (short*)(ws + 18 * Q);    // Q18-23
    short* val2  = (short*)(ws + 24 * Q);    // Q24-29
    short* w1b   = (short*)(ws + 30 * Q);    // Q30-35 (bf16 3S)
    short* w2_h  = (short*)(ws + 36 * Q);    // Q36-38
    short* w2_l  = (short*)(ws + 39 * Q);    // Q39-41
    short* cat2_h = (short*)(ws + 42 * Q);   // Q42-45
    short* cat2_l = (short*)(ws + 46 * Q);   // Q46-49
    short* t4_h  = (short*)(ws + 18 * Q);    // Q18-19
    short* t4_l  = (short*)(ws + 20 * Q);    // Q20-21
    float* h1    = ws + 22 * Q;              // Q22-25 (fp32 S)
    float* x3    = ws + 26 * Q;              // Q26-27 (fp32 S/2)
    short* vecC_h = (short*)(ws + 28 * Q);   // Q28-30
    short* vecC_l = (short*)(ws + 31 * Q);   // Q31-33
    // phase 5
    short* w3b   = (short*)(ws + 34 * Q);    // Q34-36
    float* w4    = ws + 37 * Q;              // Q37
    short* cat3_h = (short*)(ws + 38 * Q);   // Q38-39
    short* cat3_l = (short*)(ws + 40 * Q);   // Q40-41
    float* t5    = ws + 42 * Q;              // Q42-43

    // weight hi/lo offsets (shorts)
    short* WT_x1    = wtb;
    short* WT_x2    = wtb + 65536;
    short* WT_vp    = wtb + 262144;
    short* WT_xv1   = wtb + 393216;
    short* WT_xv2   = wtb + 524288;
    short* WT_o1Wv1 = wtb + 720896;
    short* WT_o1Wv2 = wtb + 786432;
    short* WT_o1Wu1 = wtb + 819200;
    short* WT_o1Wu2 = wtb + 950272;
    short* WT_o2Wv1 = wtb + 1015808;
    short* WT_o2Wu1 = wtb + 1032192;

    // Phase 0: all weight transposes + splits in one launch
    WtArgs wa;
    const float* wsrc[11] = {W_x1, W_x2, W_vp, W_xv1, W_xv2, o1_Wv1, o1_Wv2,
                             o1_Wu1, o1_Wu2, o2_Wv1, o2_Wu1};
    int wk[11] = {256, 256, 256, 512, 256, 256, 256, 512, 256, 128, 256};
    int wn[11] = {256, 768, 512, 256, 768, 256, 128, 256, 256, 128, 128};
    int off = 0;
    for (int i = 0; i < 11; i++) {
        wa.W[i] = wsrc[i]; wa.K[i] = wk[i]; wa.N[i] = wn[i];
        wa.off[i] = off; off += wk[i] * wn[i];
    }
    wa.off[11] = off;  // 1,064,960
    wt_split_all<<<off / 256, 256, 0, stream>>>(wa, wtb, wtb + WLO);

    // Phase 1: node MLP
    ln_kernel<<<NN, 256, 0, stream>>>(x, ln_g, ln_b, xln_h, xln_l);
    mfma_gemm<<<dim3(NN / 128, 4), 256, 0, stream>>>(xln_h, xln_l, WT_x1, WT_x1 + WLO,
                                                     b_x1, t1_h, t1_l, NN, 256, 256, 1);
    mfma_gemm<<<dim3(NN / 128, 12), 256, 0, stream>>>(t1_h, t1_l, WT_x2, WT_x2 + WLO,
                                                      b_x2, xh, nullptr, NN, 256, 768, 0);

    // Phase 2: sort edges by dst; node order by desc degree; CSR gather (no atomics)
    zero_kernel<<<(NN + 64 + 255) / 256, 256, 0, stream>>>(cursor, NN + 64);
    hist_kernel<<<EE / 256, 256, 0, stream>>>(edge_index, cursor);
    scan_kernel<<<1, 256, 0, stream>>>(cursor, rowptr);
    scatter_kernel<<<EE / 256, 256, 0, stream>>>(edge_index, cursor, perm);
    deg_hist_kernel<<<NN / 256, 256, 0, stream>>>(rowptr, dhist);
    deg_scan_kernel<<<1, 64, 0, stream>>>(dhist);
    deg_scatter_kernel<<<NN / 256, 256, 0, stream>>>(rowptr, dhist, nodeorder);
    node_gather_kernel<<<NN, 256, 0, stream>>>(edge_rbf, W_rbf, b_rbf, xh, vec,
                                               edge_vector, edge_index, x,
                                               perm, rowptr, nodeorder, x1, vecacc,
                                               vah, val_);

    // Phase 3: vp, vdot/vnorm, xv MLP, in-place updates
    mfma_gemm<<<dim3(3 * NN / 128, 4), 256, 0, stream>>>(vah, val_, WT_vp, WT_vp + WLO,
                                                         nullptr, vec1, nullptr,
                                                         3 * NN, 256, 256, 0);
    mfma_gemm<<<dim3(3 * NN / 128, 4), 256, 0, stream>>>(vah, val_, WT_vp + 65536,
                                                         WT_vp + WLO + 65536,
                                                         nullptr, vec2b, nullptr,
                                                         3 * NN, 256, 256, 2);
    vdot_cat_kernel<<<NN, 256, 0, stream>>>(vec1, vec2b, x1, vdot, catb_h, catb_l);
    mfma_gemm<<<dim3(NN / 128, 4), 256, 0, stream>>>(catb_h, catb_l, WT_xv1, WT_xv1 + WLO,
                                                     b_xv1, t2_h, t2_l, NN, 512, 256, 1);
    mfma_gemm<<<dim3(NN / 128, 12), 256, 0, stream>>>(t2_h, t2_l, WT_xv2, WT_xv2 + WLO,
                                                      b_xv2, xvh_h, xvh_l, NN, 256, 768, 0);
    e4_kernel<<<NN, 256, 0, stream>>>(x1, vecacc, vec1, vdot, xvh_h, xvh_l);

    // Phase 4: gated equivariant block 1
    split4_kernel<<<3 * S / 1024, 256, 0, stream>>>(vecacc, vah2, val2);
    mfma_gemm<<<dim3(3 * NN / 128, 4), 256, 0, stream>>>(vah2, val2, WT_o1Wv1, WT_o1Wv1 + WLO,
                                                         nullptr, w1b, nullptr,
                                                         3 * NN, 256, 256, 2);
    mfma_gemm<<<dim3(3 * NN / 128, 2), 256, 0, stream>>>(vah2, val2, WT_o1Wv2, WT_o1Wv2 + WLO,
                                                         nullptr, w2_h, w2_l,
                                                         3 * NN, 256, 128, 0);
    normcat_kernel<<<NN * 512 / 256, 256, 0, stream>>>(x1, w1b, cat2_h, cat2_l, 256, 256, 9);
    mfma_gemm<<<dim3(NN / 128, 4), 256, 0, stream>>>(cat2_h, cat2_l, WT_o1Wu1, WT_o1Wu1 + WLO,
                                                     o1_bu1, t4_h, t4_l, NN, 512, 256, 1);
    mfma_gemm<<<dim3(NN / 128, 4), 256, 0, stream>>>(t4_h, t4_l, WT_o1Wu2, WT_o1Wu2 + WLO,
                                                     o1_bu2, h1, nullptr, NN, 256, 256, 0);
    gate1_kernel<<<NN * 128 / 256, 256, 0, stream>>>(h1, w2_h, w2_l, x3, vecC_h, vecC_l);

    // Phase 5: gated equivariant block 2 + output
    mfma_gemm<<<dim3(3 * NN / 128, 2), 256, 0, stream>>>(vecC_h, vecC_l, WT_o2Wv1,
                                                         WT_o2Wv1 + WLO, nullptr,
                                                         w3b, nullptr, 3 * NN, 128, 128, 2);
    g12_kernel<<<3 * NN / 4, 256, 0, stream>>>(vecC_h, vecC_l, o2_Wv2, w4);
    normcat_kernel<<<NN * 256 / 256, 256, 0, stream>>>(x3, w3b, cat3_h, cat3_l, 128, 128, 8);
    mfma_gemm<<<dim3(NN / 128, 2), 256, 0, stream>>>(cat3_h, cat3_l, WT_o2Wu1, WT_o2Wu1 + WLO,
                                                     o2_bu1, t5, nullptr, NN, 256, 128, 1);
    final_kernel<<<NN / 4, 256, 0, stream>>>(t5, o2_Wu2, o2_bu2, w4, out);
}